// Round 7
// baseline (161.347 us; speedup 1.0000x reference)
//
#include <hip/hip_runtime.h>

#define N_POINTS 16384
#define D_FEAT   256
#define K_NB     8
#define G        12
#define NCELL    (G * G * G)      // 1728
#define PB_T     1024
#define PPT      (N_POINTS / PB_T) // 16 points per thread in block 0

__device__ __forceinline__ int clampi(int v, int lo, int hi) {
    return min(max(v, lo), hi);
}

// ---------- prep_bin: block 0 = hist+scan+scatter (reg-resident);
// ----------           blocks 1..1024 = rnorm; also zeroes accumulators ------
__global__ __launch_bounds__(PB_T) void prep_bin_kernel(const float* __restrict__ coords,
                                                        const float* __restrict__ feat,
                                                        int* __restrict__ cell_start,
                                                        float4* __restrict__ sorted,
                                                        float* __restrict__ rnorm,
                                                        unsigned long long* __restrict__ total,
                                                        unsigned int* __restrict__ cnt) {
    const int tid  = threadIdx.x;
    const int lane = tid & 63;
    const int wave = tid >> 6;

    if (blockIdx.x == 0) {
        __shared__ int h[NCELL];     // 6.75 KB
        __shared__ int cur[NCELL];   // 6.75 KB
        __shared__ int wt[16];

        if (tid == 0) { *total = 0ull; *cnt = 0u; }
        for (int c = tid; c < NCELL; c += PB_T) h[c] = 0;

        // ---- burst-load all 16 points/thread into registers ----
        float px[PPT], py[PPT], pz[PPT];
        int   cc[PPT];
        #pragma unroll
        for (int t = 0; t < PPT; ++t) {
            const int i = tid + t * PB_T;
            px[t] = coords[3 * i];
            py[t] = coords[3 * i + 1];
            pz[t] = coords[3 * i + 2];
        }
        __syncthreads();             // h[] zeroed

        #pragma unroll
        for (int t = 0; t < PPT; ++t) {
            const int cx = clampi((int)(px[t] * (float)G), 0, G - 1);
            const int cy = clampi((int)(py[t] * (float)G), 0, G - 1);
            const int cz = clampi((int)(pz[t] * (float)G), 0, G - 1);
            cc[t] = (cz * G + cy) * G + cx;
            atomicAdd(&h[cc[t]], 1);
        }
        __syncthreads();

        // ---- exclusive scan: 2 cells per thread ----
        const int t2 = tid * 2;
        int a = (t2 < NCELL) ? h[t2] : 0;
        int b = (t2 + 1 < NCELL) ? h[t2 + 1] : 0;
        int v = a + b;
        #pragma unroll
        for (int off = 1; off < 64; off <<= 1) {
            int o = __shfl_up(v, off, 64);
            if (lane >= off) v += o;
        }
        if (lane == 63) wt[wave] = v;
        __syncthreads();
        int woff = 0;
        #pragma unroll
        for (int w = 0; w < 16; ++w) woff += (w < wave) ? wt[w] : 0;
        const int ex = woff + v - a - b;
        if (t2 < NCELL)     { cur[t2]     = ex;     cell_start[t2]     = ex; }
        if (t2 + 1 < NCELL) { cur[t2 + 1] = ex + a; cell_start[t2 + 1] = ex + a; }
        if (tid == 0) cell_start[NCELL] = N_POINTS;
        __syncthreads();

        // ---- scatter straight from registers ----
        #pragma unroll
        for (int t = 0; t < PPT; ++t) {
            const int slot = atomicAdd(&cur[cc[t]], 1);
            sorted[slot] = make_float4(px[t], py[t], pz[t],
                                       __int_as_float(tid + t * PB_T));
        }
    } else {
        // ---- rnorm: 16 rows per block, one row per wave ----
        const int row = (blockIdx.x - 1) * 16 + wave;
        const float4* f4 = reinterpret_cast<const float4*>(feat + (size_t)row * D_FEAT);
        float4 u = f4[lane];
        float s = u.x * u.x + u.y * u.y + u.z * u.z + u.w * u.w;
        #pragma unroll
        for (int off = 32; off > 0; off >>= 1) s += __shfl_xor(s, off, 64);
        if (lane == 0) rnorm[row] = 1.0f / fmaxf(sqrtf(s), 1e-12f);
    }
}

// ---------- knn + cosine + fixed-point global accumulate --------------------
__global__ __launch_bounds__(256) void knn_cos_kernel(const float4* __restrict__ sorted,
                                                      const int* __restrict__ cell_start,
                                                      const float* __restrict__ feat,
                                                      const float* __restrict__ rnorm,
                                                      unsigned long long* __restrict__ total,
                                                      unsigned int* __restrict__ cnt,
                                                      float* __restrict__ out) {
    const int tid  = threadIdx.x;
    const int lane = tid & 63;
    const int wave = tid >> 6;
    const int q    = blockIdx.x * 4 + wave;       // sorted position

    const float4 qp = sorted[q];
    const float xi = qp.x, yi = qp.y, zi = qp.z;
    const int qorig = __float_as_int(qp.w);
    const int cx = clampi((int)(xi * (float)G), 0, G - 1);
    const int cy = clampi((int)(yi * (float)G), 0, G - 1);
    const int cz = clampi((int)(zi * (float)G), 0, G - 1);
    const int x0 = max(cx - 1, 0), x1 = min(cx + 1, G - 1);

    // lanes 0..8 fetch the 9 segment bounds in parallel
    int sv = 0, ev = 0;
    {
        const int dz = lane / 3 - 1, dy = lane % 3 - 1;   // meaningful for lane<9
        const int z = cz + dz, y = cy + dy;
        const bool valid = (lane < 9) && z >= 0 && z < G && y >= 0 && y < G;
        if (valid) {
            const int rowb = (z * G + y) * G;
            sv = cell_start[rowb + x0];
            ev = cell_start[rowb + x1 + 1];
        }
    }

    // ---- branchless per-lane top-2 ----
    const unsigned long long INF = 0xFFFFFFFFFFFFFFFFull;
    unsigned long long k0 = INF, k1 = INF;

    #pragma unroll
    for (int r = 0; r < 9; ++r) {
        const int s = __shfl(sv, r, 64);
        const int e = __shfl(ev, r, 64);
        for (int bpos = s; bpos < e; bpos += 64) {
            const int idx = bpos + lane;
            if (idx < e) {
                const float4 p = sorted[idx];
                const float dx = p.x - xi, dyv = p.y - yi, dzv = p.z - zi;
                const float d2 = fmaf(dx, dx, fmaf(dyv, dyv, dzv * dzv));
                const int j = __float_as_int(p.w);
                unsigned long long key =
                    ((unsigned long long)__float_as_uint(d2) << 32) | (unsigned int)j;
                key = (j == qorig) ? INF : key;
                const unsigned long long lo = (key < k0) ? key : k0;
                const unsigned long long hi = (key < k0) ? k0 : key;
                k0 = lo;
                k1 = (hi < k1) ? hi : k1;
            }
        }
    }

    // ---- merge: 8 rounds of wave-min over per-lane heads ----
    int nb[8];
    #pragma unroll
    for (int r = 0; r < K_NB; ++r) {
        unsigned long long m = k0;
        #pragma unroll
        for (int off = 32; off > 0; off >>= 1) {
            unsigned long long o = __shfl_xor(m, off, 64);
            m = (o < m) ? o : m;
        }
        const bool won = (k0 == m);
        k0 = won ? k1 : k0;
        k1 = won ? INF : k1;
        nb[r] = (int)(m & 0xFFFFFFFFu);
    }

    // ---- cosine: precomputed rnorm, single-value linear reduce ----
    const float4* fq = reinterpret_cast<const float4*>(feat + (size_t)qorig * D_FEAT);
    const float4 aq = fq[lane];
    const float rq = rnorm[qorig];
    float racc = 0.0f;
    #pragma unroll
    for (int r = 0; r < K_NB; ++r) {
        const int j = (nb[r] < 0) ? qorig : nb[r];
        const float4* fn = reinterpret_cast<const float4*>(feat + (size_t)j * D_FEAT);
        const float4 b = fn[lane];
        const float s = fmaf(aq.x, b.x, fmaf(aq.y, b.y, fmaf(aq.z, b.z, aq.w * b.w)));
        racc = fmaf(s, rq * rnorm[j], racc);
    }
    #pragma unroll
    for (int off = 32; off > 0; off >>= 1) racc += __shfl_xor(racc, off, 64);
    const float wval = (float)K_NB - racc;        // sum of (1 - cos)

    // ---- deterministic fixed-point accumulate; last block writes out ----
    __shared__ float wacc[4];
    if (lane == 0) wacc[wave] = wval;
    __syncthreads();
    if (tid == 0) {
        const double bval = (double)wacc[0] + (double)wacc[1]
                          + (double)wacc[2] + (double)wacc[3];
        const long long qfx = llrint(bval * 4294967296.0);
        atomicAdd(total, (unsigned long long)qfx);
        __threadfence();
        const unsigned int prev = atomicAdd(cnt, 1u);
        if (prev == (unsigned int)(gridDim.x - 1)) {
            __threadfence();
            const unsigned long long t = atomicAdd(total, 0ull);  // coherent read
            const double sum = (double)(long long)t * (1.0 / 4294967296.0);
            out[0] = (float)(0.02 * sum / (double)(N_POINTS * K_NB));
        }
    }
}

// ---------- launch ----------------------------------------------------------
extern "C" void kernel_launch(void* const* d_in, const int* in_sizes, int n_in,
                              void* d_out, int out_size, void* d_ws, size_t ws_size,
                              hipStream_t stream) {
    const float* feat   = (const float*)d_in[0];   // (16384, 256) f32
    const float* coords = (const float*)d_in[1];   // (16384, 3)  f32
    float* out = (float*)d_out;

    char* ws = (char*)d_ws;
    float4* sorted     = (float4*)ws;                           // 262144 B
    int*    cell_start = (int*)(ws + 262144);                   // 8192 B
    float*  rnorm      = (float*)(ws + 262144 + 8192);          // 65536 B
    unsigned long long* total = (unsigned long long*)(ws + 262144 + 8192 + 65536);
    unsigned int*       cnt   = (unsigned int*)(ws + 262144 + 8192 + 65536 + 8);

    prep_bin_kernel<<<1 + N_POINTS / 16, PB_T, 0, stream>>>(coords, feat, cell_start,
                                                            sorted, rnorm, total, cnt);
    knn_cos_kernel<<<N_POINTS / 4, 256, 0, stream>>>(sorted, cell_start, feat,
                                                     rnorm, total, cnt, out);
}

// Round 8
// 50.460 us; speedup vs baseline: 3.1975x; 3.1975x over previous
//
#include <hip/hip_runtime.h>

#define N_POINTS 16384
#define D_FEAT   256
#define K_NB     8
#define G        12
#define NCELL    (G * G * G)      // 1728
#define PB_T     1024
#define PPT      (N_POINTS / PB_T) // 16 points per thread in block 0

__device__ __forceinline__ int clampi(int v, int lo, int hi) {
    return min(max(v, lo), hi);
}

// ---------- prep_bin: block 0 = hist+scan+scatter (reg-resident);
// ----------           blocks 1..1024 = rnorm ---------------------------------
__global__ __launch_bounds__(PB_T) void prep_bin_kernel(const float* __restrict__ coords,
                                                        const float* __restrict__ feat,
                                                        int* __restrict__ cell_start,
                                                        float4* __restrict__ sorted,
                                                        float* __restrict__ rnorm) {
    const int tid  = threadIdx.x;
    const int lane = tid & 63;
    const int wave = tid >> 6;

    if (blockIdx.x == 0) {
        __shared__ int h[NCELL];     // 6.75 KB
        __shared__ int cur[NCELL];   // 6.75 KB
        __shared__ int wt[16];

        for (int c = tid; c < NCELL; c += PB_T) h[c] = 0;

        // ---- burst-load all 16 points/thread into registers ----
        float px[PPT], py[PPT], pz[PPT];
        int   cc[PPT];
        #pragma unroll
        for (int t = 0; t < PPT; ++t) {
            const int i = tid + t * PB_T;
            px[t] = coords[3 * i];
            py[t] = coords[3 * i + 1];
            pz[t] = coords[3 * i + 2];
        }
        __syncthreads();             // h[] zeroed

        #pragma unroll
        for (int t = 0; t < PPT; ++t) {
            const int cx = clampi((int)(px[t] * (float)G), 0, G - 1);
            const int cy = clampi((int)(py[t] * (float)G), 0, G - 1);
            const int cz = clampi((int)(pz[t] * (float)G), 0, G - 1);
            cc[t] = (cz * G + cy) * G + cx;
            atomicAdd(&h[cc[t]], 1);
        }
        __syncthreads();

        // ---- exclusive scan: 2 cells per thread ----
        const int t2 = tid * 2;
        int a = (t2 < NCELL) ? h[t2] : 0;
        int b = (t2 + 1 < NCELL) ? h[t2 + 1] : 0;
        int v = a + b;
        #pragma unroll
        for (int off = 1; off < 64; off <<= 1) {
            int o = __shfl_up(v, off, 64);
            if (lane >= off) v += o;
        }
        if (lane == 63) wt[wave] = v;
        __syncthreads();
        int woff = 0;
        #pragma unroll
        for (int w = 0; w < 16; ++w) woff += (w < wave) ? wt[w] : 0;
        const int ex = woff + v - a - b;
        if (t2 < NCELL)     { cur[t2]     = ex;     cell_start[t2]     = ex; }
        if (t2 + 1 < NCELL) { cur[t2 + 1] = ex + a; cell_start[t2 + 1] = ex + a; }
        if (tid == 0) cell_start[NCELL] = N_POINTS;
        __syncthreads();

        // ---- scatter straight from registers ----
        #pragma unroll
        for (int t = 0; t < PPT; ++t) {
            const int slot = atomicAdd(&cur[cc[t]], 1);
            sorted[slot] = make_float4(px[t], py[t], pz[t],
                                       __int_as_float(tid + t * PB_T));
        }
    } else {
        // ---- rnorm: 16 rows per block, one row per wave ----
        const int row = (blockIdx.x - 1) * 16 + wave;
        const float4* f4 = reinterpret_cast<const float4*>(feat + (size_t)row * D_FEAT);
        float4 u = f4[lane];
        float s = u.x * u.x + u.y * u.y + u.z * u.z + u.w * u.w;
        #pragma unroll
        for (int off = 32; off > 0; off >>= 1) s += __shfl_xor(s, off, 64);
        if (lane == 0) rnorm[row] = 1.0f / fmaxf(sqrtf(s), 1e-12f);
    }
}

// ---------- knn + cosine: one wave per query, partial per block -------------
__global__ __launch_bounds__(256) void knn_cos_kernel(const float4* __restrict__ sorted,
                                                      const int* __restrict__ cell_start,
                                                      const float* __restrict__ feat,
                                                      const float* __restrict__ rnorm,
                                                      float* __restrict__ partial) {
    const int tid  = threadIdx.x;
    const int lane = tid & 63;
    const int wave = tid >> 6;
    const int q    = blockIdx.x * 4 + wave;       // sorted position

    const float4 qp = sorted[q];
    const float xi = qp.x, yi = qp.y, zi = qp.z;
    const int qorig = __float_as_int(qp.w);
    const int cx = clampi((int)(xi * (float)G), 0, G - 1);
    const int cy = clampi((int)(yi * (float)G), 0, G - 1);
    const int cz = clampi((int)(zi * (float)G), 0, G - 1);
    const int x0 = max(cx - 1, 0), x1 = min(cx + 1, G - 1);

    // lanes 0..8 fetch the 9 segment bounds in parallel
    int sv = 0, ev = 0;
    {
        const int dz = lane / 3 - 1, dy = lane % 3 - 1;   // meaningful for lane<9
        const int z = cz + dz, y = cy + dy;
        const bool valid = (lane < 9) && z >= 0 && z < G && y >= 0 && y < G;
        if (valid) {
            const int rowb = (z * G + y) * G;
            sv = cell_start[rowb + x0];
            ev = cell_start[rowb + x1 + 1];
        }
    }

    // ---- branchless per-lane top-2 ----
    const unsigned long long INF = 0xFFFFFFFFFFFFFFFFull;
    unsigned long long k0 = INF, k1 = INF;

    #pragma unroll
    for (int r = 0; r < 9; ++r) {
        const int s = __shfl(sv, r, 64);
        const int e = __shfl(ev, r, 64);
        for (int bpos = s; bpos < e; bpos += 64) {
            const int idx = bpos + lane;
            if (idx < e) {
                const float4 p = sorted[idx];
                const float dx = p.x - xi, dyv = p.y - yi, dzv = p.z - zi;
                const float d2 = fmaf(dx, dx, fmaf(dyv, dyv, dzv * dzv));
                const int j = __float_as_int(p.w);
                unsigned long long key =
                    ((unsigned long long)__float_as_uint(d2) << 32) | (unsigned int)j;
                key = (j == qorig) ? INF : key;
                const unsigned long long lo = (key < k0) ? key : k0;
                const unsigned long long hi = (key < k0) ? k0 : key;
                k0 = lo;
                k1 = (hi < k1) ? hi : k1;
            }
        }
    }

    // ---- merge: 8 rounds of wave-min over per-lane heads ----
    int nb[8];
    #pragma unroll
    for (int r = 0; r < K_NB; ++r) {
        unsigned long long m = k0;
        #pragma unroll
        for (int off = 32; off > 0; off >>= 1) {
            unsigned long long o = __shfl_xor(m, off, 64);
            m = (o < m) ? o : m;
        }
        const bool won = (k0 == m);
        k0 = won ? k1 : k0;
        k1 = won ? INF : k1;
        nb[r] = (int)(m & 0xFFFFFFFFu);
    }

    // ---- cosine: precomputed rnorm, single-value linear reduce ----
    const float4* fq = reinterpret_cast<const float4*>(feat + (size_t)qorig * D_FEAT);
    const float4 aq = fq[lane];
    const float rq = rnorm[qorig];
    float racc = 0.0f;
    #pragma unroll
    for (int r = 0; r < K_NB; ++r) {
        const int j = (nb[r] < 0) ? qorig : nb[r];
        const float4* fn = reinterpret_cast<const float4*>(feat + (size_t)j * D_FEAT);
        const float4 b = fn[lane];
        const float s = fmaf(aq.x, b.x, fmaf(aq.y, b.y, fmaf(aq.z, b.z, aq.w * b.w)));
        racc = fmaf(s, rq * rnorm[j], racc);
    }
    #pragma unroll
    for (int off = 32; off > 0; off >>= 1) racc += __shfl_xor(racc, off, 64);
    const float wval = (float)K_NB - racc;        // sum of (1 - cos)

    __shared__ float wacc[4];
    if (lane == 0) wacc[wave] = wval;
    __syncthreads();
    if (tid == 0)
        partial[blockIdx.x] = wacc[0] + wacc[1] + wacc[2] + wacc[3];
}

// ---------- final reduction (4096 partials, fixed order) --------------------
__global__ __launch_bounds__(256) void reduce_kernel(const float* __restrict__ partial,
                                                     float* __restrict__ out) {
    const int tid  = threadIdx.x;
    const int lane = tid & 63;
    const int wave = tid >> 6;
    float s = 0.0f;
    for (int j = tid; j < N_POINTS / 4; j += 256) s += partial[j];
    #pragma unroll
    for (int off = 32; off > 0; off >>= 1) s += __shfl_xor(s, off, 64);
    __shared__ float sm[4];
    if (lane == 0) sm[wave] = s;
    __syncthreads();
    if (tid == 0)
        out[0] = 0.02f * (sm[0] + sm[1] + sm[2] + sm[3]) / (float)(N_POINTS * K_NB);
}

// ---------- launch ----------------------------------------------------------
extern "C" void kernel_launch(void* const* d_in, const int* in_sizes, int n_in,
                              void* d_out, int out_size, void* d_ws, size_t ws_size,
                              hipStream_t stream) {
    const float* feat   = (const float*)d_in[0];   // (16384, 256) f32
    const float* coords = (const float*)d_in[1];   // (16384, 3)  f32
    float* out = (float*)d_out;

    char* ws = (char*)d_ws;
    float4* sorted     = (float4*)ws;                          // 262144 B
    int*    cell_start = (int*)(ws + 262144);                  // 8192 B
    float*  rnorm      = (float*)(ws + 262144 + 8192);         // 65536 B
    float*  partial    = (float*)(ws + 262144 + 8192 + 65536); // 16384 B

    prep_bin_kernel<<<1 + N_POINTS / 16, PB_T, 0, stream>>>(coords, feat,
                                                            cell_start, sorted, rnorm);
    knn_cos_kernel<<<N_POINTS / 4, 256, 0, stream>>>(sorted, cell_start, feat,
                                                     rnorm, partial);
    reduce_kernel<<<1, 256, 0, stream>>>(partial, out);
}

// Round 9
// 45.991 us; speedup vs baseline: 3.5083x; 1.0972x over previous
//
#include <hip/hip_runtime.h>

#define N_POINTS 16384
#define D_FEAT   256
#define K_NB     8
#define G        12
#define NCELL    (G * G * G)      // 1728
#define PB_T     1024
#define PPT      (N_POINTS / PB_T) // 16 points per thread in block 0

__device__ __forceinline__ int clampi(int v, int lo, int hi) {
    return min(max(v, lo), hi);
}

// ---------- prep_bin: block 0 = hist+scan+scatter (reg-resident);
// ----------           blocks 1..1024 = rnorm --------------------------------
__global__ __launch_bounds__(PB_T) void prep_bin_kernel(const float* __restrict__ coords,
                                                        const float* __restrict__ feat,
                                                        int* __restrict__ cell_start,
                                                        float4* __restrict__ sorted,
                                                        float* __restrict__ rnorm) {
    const int tid  = threadIdx.x;
    const int lane = tid & 63;
    const int wave = tid >> 6;

    if (blockIdx.x == 0) {
        __shared__ int h[NCELL];     // 6.75 KB
        __shared__ int cur[NCELL];   // 6.75 KB
        __shared__ int wt[16];

        for (int c = tid; c < NCELL; c += PB_T) h[c] = 0;

        // ---- burst-load all 16 points/thread into registers ----
        float px[PPT], py[PPT], pz[PPT];
        int   cc[PPT];
        #pragma unroll
        for (int t = 0; t < PPT; ++t) {
            const int i = tid + t * PB_T;
            px[t] = coords[3 * i];
            py[t] = coords[3 * i + 1];
            pz[t] = coords[3 * i + 2];
        }
        __syncthreads();             // h[] zeroed

        #pragma unroll
        for (int t = 0; t < PPT; ++t) {
            const int cx = clampi((int)(px[t] * (float)G), 0, G - 1);
            const int cy = clampi((int)(py[t] * (float)G), 0, G - 1);
            const int cz = clampi((int)(pz[t] * (float)G), 0, G - 1);
            cc[t] = (cz * G + cy) * G + cx;
            atomicAdd(&h[cc[t]], 1);
        }
        __syncthreads();

        // ---- exclusive scan: 2 cells per thread ----
        const int t2 = tid * 2;
        int a = (t2 < NCELL) ? h[t2] : 0;
        int b = (t2 + 1 < NCELL) ? h[t2 + 1] : 0;
        int v = a + b;
        #pragma unroll
        for (int off = 1; off < 64; off <<= 1) {
            int o = __shfl_up(v, off, 64);
            if (lane >= off) v += o;
        }
        if (lane == 63) wt[wave] = v;
        __syncthreads();
        int woff = 0;
        #pragma unroll
        for (int w = 0; w < 16; ++w) woff += (w < wave) ? wt[w] : 0;
        const int ex = woff + v - a - b;
        if (t2 < NCELL)     { cur[t2]     = ex;     cell_start[t2]     = ex; }
        if (t2 + 1 < NCELL) { cur[t2 + 1] = ex + a; cell_start[t2 + 1] = ex + a; }
        if (tid == 0) cell_start[NCELL] = N_POINTS;
        __syncthreads();

        // ---- scatter straight from registers ----
        #pragma unroll
        for (int t = 0; t < PPT; ++t) {
            const int slot = atomicAdd(&cur[cc[t]], 1);
            sorted[slot] = make_float4(px[t], py[t], pz[t],
                                       __int_as_float(tid + t * PB_T));
        }
    } else {
        // ---- rnorm: 16 rows per block, one row per wave ----
        const int row = (blockIdx.x - 1) * 16 + wave;
        const float4* f4 = reinterpret_cast<const float4*>(feat + (size_t)row * D_FEAT);
        float4 u = f4[lane];
        float s = u.x * u.x + u.y * u.y + u.z * u.z + u.w * u.w;
        #pragma unroll
        for (int off = 32; off > 0; off >>= 1) s += __shfl_xor(s, off, 64);
        if (lane == 0) rnorm[row] = 1.0f / fmaxf(sqrtf(s), 1e-12f);
    }
}

// 32-bit key: truncated d2 bits (exp + 11 mantissa) << 14 | sorted index.
// d2 < 1.0 here, so bits < 0x3F800000 and the shifted key fits in 32 bits.
#define PROC32(p, idxv)                                                       \
    {                                                                         \
        const float _dx = (p).x - xi, _dy = (p).y - yi, _dz = (p).z - zi;     \
        const float _d2 = fmaf(_dx, _dx, fmaf(_dy, _dy, _dz * _dz));          \
        unsigned _key = ((__float_as_uint(_d2) >> 12) << 14) | (unsigned)(idxv); \
        _key = ((idxv) == q) ? 0xFFFFFFFFu : _key;                            \
        const unsigned _lo = min(_key, k0);                                   \
        const unsigned _hi = max(_key, k0);                                   \
        k0 = _lo;                                                             \
        k1 = min(_hi, k1);                                                    \
    }

// ---------- knn + cosine: one wave per query, partial per block -------------
__global__ __launch_bounds__(256) void knn_cos_kernel(const float4* __restrict__ sorted,
                                                      const int* __restrict__ cell_start,
                                                      const float* __restrict__ feat,
                                                      const float* __restrict__ rnorm,
                                                      float* __restrict__ partial) {
    const int tid  = threadIdx.x;
    const int lane = tid & 63;
    const int wave = tid >> 6;
    const int q    = blockIdx.x * 4 + wave;       // sorted position

    const float4 qp = sorted[q];
    const float xi = qp.x, yi = qp.y, zi = qp.z;
    const int qorig = __float_as_int(qp.w);
    const int cx = clampi((int)(xi * (float)G), 0, G - 1);
    const int cy = clampi((int)(yi * (float)G), 0, G - 1);
    const int cz = clampi((int)(zi * (float)G), 0, G - 1);
    const int x0 = max(cx - 1, 0), x1 = min(cx + 1, G - 1);

    // lanes 0..8 fetch the 9 segment bounds in parallel
    int sv = 0, ev = 0;
    {
        const int dz = lane / 3 - 1, dy = lane % 3 - 1;   // meaningful for lane<9
        const int z = cz + dz, y = cy + dy;
        const bool valid = (lane < 9) && z >= 0 && z < G && y >= 0 && y < G;
        if (valid) {
            const int rowb = (z * G + y) * G;
            sv = cell_start[rowb + x0];
            ev = cell_start[rowb + x1 + 1];
        }
    }

    int segS[9], segE[9];
    #pragma unroll
    for (int r = 0; r < 9; ++r) {
        segS[r] = __shfl(sv, r, 64);
        segE[r] = __shfl(ev, r, 64);
    }

    // ---- prefetch first 64 candidates of every segment (independent loads) --
    float4 pf[9];
    #pragma unroll
    for (int r = 0; r < 9; ++r) {
        const int idx = segS[r] + lane;
        pf[r] = sorted[min(idx, N_POINTS - 1)];   // clamped; masked in use
    }

    // ---- branchless per-lane top-2 over prefetched + tail candidates ----
    unsigned k0 = 0xFFFFFFFFu, k1 = 0xFFFFFFFFu;
    #pragma unroll
    for (int r = 0; r < 9; ++r) {
        const int idx = segS[r] + lane;
        if (idx < segE[r]) PROC32(pf[r], idx);
        // tail (segment longer than 64 points — rare)
        for (int b = segS[r] + 64; b < segE[r]; b += 64) {
            const int idx2 = b + lane;
            if (idx2 < segE[r]) {
                const float4 p = sorted[idx2];
                PROC32(p, idx2);
            }
        }
    }

    // ---- merge: 8 rounds of 32-bit wave-min over per-lane heads ----
    int nb[8];
    #pragma unroll
    for (int r = 0; r < K_NB; ++r) {
        unsigned m = k0;
        #pragma unroll
        for (int off = 32; off > 0; off >>= 1)
            m = min(m, (unsigned)__shfl_xor((int)m, off, 64));
        const bool won = (k0 == m);
        k0 = won ? k1 : k0;
        k1 = won ? 0xFFFFFFFFu : k1;
        nb[r] = (int)(m & 0x3FFFu);               // sorted index of neighbor
    }

    // ---- gather neighbor ids + rnorms first (independent loads) ----
    int jj[8];
    #pragma unroll
    for (int r = 0; r < K_NB; ++r) jj[r] = __float_as_int(sorted[nb[r]].w);
    float rn[8];
    #pragma unroll
    for (int r = 0; r < K_NB; ++r) rn[r] = rnorm[jj[r]];

    // ---- cosine: single-value linear reduce ----
    const float4* fq = reinterpret_cast<const float4*>(feat + (size_t)qorig * D_FEAT);
    const float4 aq = fq[lane];
    const float rq = rnorm[qorig];
    float racc = 0.0f;
    #pragma unroll
    for (int r = 0; r < K_NB; ++r) {
        const float4 b =
            reinterpret_cast<const float4*>(feat + (size_t)jj[r] * D_FEAT)[lane];
        const float s = fmaf(aq.x, b.x, fmaf(aq.y, b.y, fmaf(aq.z, b.z, aq.w * b.w)));
        racc = fmaf(s, rq * rn[r], racc);
    }
    #pragma unroll
    for (int off = 32; off > 0; off >>= 1) racc += __shfl_xor(racc, off, 64);
    const float wval = (float)K_NB - racc;        // sum of (1 - cos)

    __shared__ float wacc[4];
    if (lane == 0) wacc[wave] = wval;
    __syncthreads();
    if (tid == 0)
        partial[blockIdx.x] = wacc[0] + wacc[1] + wacc[2] + wacc[3];
}

// ---------- final reduction (4096 partials, fixed order) --------------------
__global__ __launch_bounds__(256) void reduce_kernel(const float* __restrict__ partial,
                                                     float* __restrict__ out) {
    const int tid  = threadIdx.x;
    const int lane = tid & 63;
    const int wave = tid >> 6;
    float s = 0.0f;
    for (int j = tid; j < N_POINTS / 4; j += 256) s += partial[j];
    #pragma unroll
    for (int off = 32; off > 0; off >>= 1) s += __shfl_xor(s, off, 64);
    __shared__ float sm[4];
    if (lane == 0) sm[wave] = s;
    __syncthreads();
    if (tid == 0)
        out[0] = 0.02f * (sm[0] + sm[1] + sm[2] + sm[3]) / (float)(N_POINTS * K_NB);
}

// ---------- launch ----------------------------------------------------------
extern "C" void kernel_launch(void* const* d_in, const int* in_sizes, int n_in,
                              void* d_out, int out_size, void* d_ws, size_t ws_size,
                              hipStream_t stream) {
    const float* feat   = (const float*)d_in[0];   // (16384, 256) f32
    const float* coords = (const float*)d_in[1];   // (16384, 3)  f32
    float* out = (float*)d_out;

    char* ws = (char*)d_ws;
    float4* sorted     = (float4*)ws;                          // 262144 B
    int*    cell_start = (int*)(ws + 262144);                  // 8192 B
    float*  rnorm      = (float*)(ws + 262144 + 8192);         // 65536 B
    float*  partial    = (float*)(ws + 262144 + 8192 + 65536); // 16384 B

    prep_bin_kernel<<<1 + N_POINTS / 16, PB_T, 0, stream>>>(coords, feat,
                                                            cell_start, sorted, rnorm);
    knn_cos_kernel<<<N_POINTS / 4, 256, 0, stream>>>(sorted, cell_start, feat,
                                                     rnorm, partial);
    reduce_kernel<<<1, 256, 0, stream>>>(partial, out);
}

// Round 10
// 45.013 us; speedup vs baseline: 3.5844x; 1.0217x over previous
//
#include <hip/hip_runtime.h>

#define N_POINTS 16384
#define D_FEAT   256
#define K_NB     8
#define G        16
#define NCELL    (G * G * G)      // 4096
#define PB_T     1024
#define PPT      (N_POINTS / PB_T) // 16 points per thread in block 0
#define CPT      (NCELL / PB_T)    // 4 cells per thread in the scan

__device__ __forceinline__ int clampi(int v, int lo, int hi) {
    return min(max(v, lo), hi);
}

// ---------- prep_bin: block 0 = hist+scan+scatter (reg-resident);
// ----------           blocks 1..1024 = rnorm --------------------------------
__global__ __launch_bounds__(PB_T) void prep_bin_kernel(const float* __restrict__ coords,
                                                        const float* __restrict__ feat,
                                                        int* __restrict__ cell_start,
                                                        float4* __restrict__ sorted,
                                                        float* __restrict__ rnorm) {
    const int tid  = threadIdx.x;
    const int lane = tid & 63;
    const int wave = tid >> 6;

    if (blockIdx.x == 0) {
        __shared__ int h[NCELL];     // 16 KB
        __shared__ int cur[NCELL];   // 16 KB
        __shared__ int wt[16];

        for (int c = tid; c < NCELL; c += PB_T) h[c] = 0;

        // ---- burst-load all 16 points/thread into registers ----
        float px[PPT], py[PPT], pz[PPT];
        int   cc[PPT];
        #pragma unroll
        for (int t = 0; t < PPT; ++t) {
            const int i = tid + t * PB_T;
            px[t] = coords[3 * i];
            py[t] = coords[3 * i + 1];
            pz[t] = coords[3 * i + 2];
        }
        __syncthreads();             // h[] zeroed

        #pragma unroll
        for (int t = 0; t < PPT; ++t) {
            const int cx = clampi((int)(px[t] * (float)G), 0, G - 1);
            const int cy = clampi((int)(py[t] * (float)G), 0, G - 1);
            const int cz = clampi((int)(pz[t] * (float)G), 0, G - 1);
            cc[t] = (cz * G + cy) * G + cx;
            atomicAdd(&h[cc[t]], 1);
        }
        __syncthreads();

        // ---- exclusive scan: 4 cells per thread ----
        const int t4 = tid * CPT;
        int c[CPT];
        int tot = 0;
        #pragma unroll
        for (int k = 0; k < CPT; ++k) { c[k] = h[t4 + k]; tot += c[k]; }
        int v = tot;
        #pragma unroll
        for (int off = 1; off < 64; off <<= 1) {
            int o = __shfl_up(v, off, 64);
            if (lane >= off) v += o;
        }
        if (lane == 63) wt[wave] = v;
        __syncthreads();
        int woff = 0;
        #pragma unroll
        for (int w = 0; w < 16; ++w) woff += (w < wave) ? wt[w] : 0;
        int ex = woff + v - tot;
        #pragma unroll
        for (int k = 0; k < CPT; ++k) {
            cur[t4 + k] = ex;
            cell_start[t4 + k] = ex;
            ex += c[k];
        }
        if (tid == 0) cell_start[NCELL] = N_POINTS;
        __syncthreads();

        // ---- scatter straight from registers ----
        #pragma unroll
        for (int t = 0; t < PPT; ++t) {
            const int slot = atomicAdd(&cur[cc[t]], 1);
            sorted[slot] = make_float4(px[t], py[t], pz[t],
                                       __int_as_float(tid + t * PB_T));
        }
    } else {
        // ---- rnorm: 16 rows per block, one row per wave ----
        const int row = (blockIdx.x - 1) * 16 + wave;
        const float4* f4 = reinterpret_cast<const float4*>(feat + (size_t)row * D_FEAT);
        float4 u = f4[lane];
        float s = u.x * u.x + u.y * u.y + u.z * u.z + u.w * u.w;
        #pragma unroll
        for (int off = 32; off > 0; off >>= 1) s += __shfl_xor(s, off, 64);
        if (lane == 0) rnorm[row] = 1.0f / fmaxf(sqrtf(s), 1e-12f);
    }
}

// 32-bit key: truncated d2 bits (exp + 11 mantissa) << 14 | sorted index.
// d2 < 0.106 in a 3x3x3 neighborhood of w=1/16, so (bits>>12)<<14 fits u32.
#define PROC32(p, idxv)                                                       \
    {                                                                         \
        const float _dx = (p).x - xi, _dy = (p).y - yi, _dz = (p).z - zi;     \
        const float _d2 = fmaf(_dx, _dx, fmaf(_dy, _dy, _dz * _dz));          \
        unsigned _key = ((__float_as_uint(_d2) >> 12) << 14) | (unsigned)(idxv); \
        _key = ((idxv) == q) ? 0xFFFFFFFFu : _key;                            \
        const unsigned _lo = min(_key, k0);                                   \
        const unsigned _hi = max(_key, k0);                                   \
        k0 = _lo;                                                             \
        k1 = min(_hi, k1);                                                    \
    }

// ---------- knn + cosine: one wave per query, partial per block -------------
__global__ __launch_bounds__(256) void knn_cos_kernel(const float4* __restrict__ sorted,
                                                      const int* __restrict__ cell_start,
                                                      const float* __restrict__ feat,
                                                      const float* __restrict__ rnorm,
                                                      float* __restrict__ partial) {
    const int tid  = threadIdx.x;
    const int lane = tid & 63;
    const int wave = tid >> 6;
    const int q    = blockIdx.x * 4 + wave;       // sorted position

    const float4 qp = sorted[q];
    const float xi = qp.x, yi = qp.y, zi = qp.z;
    const int qorig = __float_as_int(qp.w);
    const int cx = clampi((int)(xi * (float)G), 0, G - 1);
    const int cy = clampi((int)(yi * (float)G), 0, G - 1);
    const int cz = clampi((int)(zi * (float)G), 0, G - 1);
    const int x0 = max(cx - 1, 0), x1 = min(cx + 1, G - 1);

    // lanes 0..8 fetch the 9 segment bounds in parallel
    int sv = 0, ev = 0;
    {
        const int dz = lane / 3 - 1, dy = lane % 3 - 1;   // meaningful for lane<9
        const int z = cz + dz, y = cy + dy;
        const bool valid = (lane < 9) && z >= 0 && z < G && y >= 0 && y < G;
        if (valid) {
            const int rowb = (z * G + y) * G;
            sv = cell_start[rowb + x0];
            ev = cell_start[rowb + x1 + 1];
        }
    }

    int segS[9], segE[9];
    #pragma unroll
    for (int r = 0; r < 9; ++r) {
        segS[r] = __shfl(sv, r, 64);
        segE[r] = __shfl(ev, r, 64);
    }

    // ---- prefetch first 64 candidates of every segment (independent loads) --
    float4 pf[9];
    #pragma unroll
    for (int r = 0; r < 9; ++r) {
        const int idx = segS[r] + lane;
        pf[r] = sorted[min(idx, N_POINTS - 1)];   // clamped; masked in use
    }

    // ---- branchless per-lane top-2 over prefetched + tail candidates ----
    unsigned k0 = 0xFFFFFFFFu, k1 = 0xFFFFFFFFu;
    #pragma unroll
    for (int r = 0; r < 9; ++r) {
        const int idx = segS[r] + lane;
        if (idx < segE[r]) PROC32(pf[r], idx);
        // tail (segment longer than 64 points — very rare at G=16)
        for (int b = segS[r] + 64; b < segE[r]; b += 64) {
            const int idx2 = b + lane;
            if (idx2 < segE[r]) {
                const float4 p = sorted[idx2];
                PROC32(p, idx2);
            }
        }
    }

    // ---- merge: 8 rounds of 32-bit wave-min over per-lane heads ----
    int nb[8];
    #pragma unroll
    for (int r = 0; r < K_NB; ++r) {
        unsigned m = k0;
        #pragma unroll
        for (int off = 32; off > 0; off >>= 1)
            m = min(m, (unsigned)__shfl_xor((int)m, off, 64));
        const bool won = (k0 == m);
        k0 = won ? k1 : k0;
        k1 = won ? 0xFFFFFFFFu : k1;
        nb[r] = (int)(m & 0x3FFFu);               // sorted index of neighbor
    }

    // ---- gather neighbor ids + rnorms first (independent loads) ----
    int jj[8];
    #pragma unroll
    for (int r = 0; r < K_NB; ++r) jj[r] = __float_as_int(sorted[nb[r]].w);
    float rn[8];
    #pragma unroll
    for (int r = 0; r < K_NB; ++r) rn[r] = rnorm[jj[r]];

    // ---- cosine: single-value linear reduce ----
    const float4* fq = reinterpret_cast<const float4*>(feat + (size_t)qorig * D_FEAT);
    const float4 aq = fq[lane];
    const float rq = rnorm[qorig];
    float racc = 0.0f;
    #pragma unroll
    for (int r = 0; r < K_NB; ++r) {
        const float4 b =
            reinterpret_cast<const float4*>(feat + (size_t)jj[r] * D_FEAT)[lane];
        const float s = fmaf(aq.x, b.x, fmaf(aq.y, b.y, fmaf(aq.z, b.z, aq.w * b.w)));
        racc = fmaf(s, rq * rn[r], racc);
    }
    #pragma unroll
    for (int off = 32; off > 0; off >>= 1) racc += __shfl_xor(racc, off, 64);
    const float wval = (float)K_NB - racc;        // sum of (1 - cos)

    __shared__ float wacc[4];
    if (lane == 0) wacc[wave] = wval;
    __syncthreads();
    if (tid == 0)
        partial[blockIdx.x] = wacc[0] + wacc[1] + wacc[2] + wacc[3];
}

// ---------- final reduction (4096 partials, fixed order) --------------------
__global__ __launch_bounds__(256) void reduce_kernel(const float* __restrict__ partial,
                                                     float* __restrict__ out) {
    const int tid  = threadIdx.x;
    const int lane = tid & 63;
    const int wave = tid >> 6;
    float s = 0.0f;
    for (int j = tid; j < N_POINTS / 4; j += 256) s += partial[j];
    #pragma unroll
    for (int off = 32; off > 0; off >>= 1) s += __shfl_xor(s, off, 64);
    __shared__ float sm[4];
    if (lane == 0) sm[wave] = s;
    __syncthreads();
    if (tid == 0)
        out[0] = 0.02f * (sm[0] + sm[1] + sm[2] + sm[3]) / (float)(N_POINTS * K_NB);
}

// ---------- launch ----------------------------------------------------------
extern "C" void kernel_launch(void* const* d_in, const int* in_sizes, int n_in,
                              void* d_out, int out_size, void* d_ws, size_t ws_size,
                              hipStream_t stream) {
    const float* feat   = (const float*)d_in[0];   // (16384, 256) f32
    const float* coords = (const float*)d_in[1];   // (16384, 3)  f32
    float* out = (float*)d_out;

    char* ws = (char*)d_ws;
    float4* sorted     = (float4*)ws;                          // 262144 B
    int*    cell_start = (int*)(ws + 262144);                  // 16388 B
    float*  rnorm      = (float*)(ws + 262144 + 16640);        // 65536 B
    float*  partial    = (float*)(ws + 262144 + 16640 + 65536);// 16384 B

    prep_bin_kernel<<<1 + N_POINTS / 16, PB_T, 0, stream>>>(coords, feat,
                                                            cell_start, sorted, rnorm);
    knn_cos_kernel<<<N_POINTS / 4, 256, 0, stream>>>(sorted, cell_start, feat,
                                                     rnorm, partial);
    reduce_kernel<<<1, 256, 0, stream>>>(partial, out);
}

// Round 11
// 43.168 us; speedup vs baseline: 3.7376x; 1.0427x over previous
//
#include <hip/hip_runtime.h>

#define N_POINTS 16384
#define D_FEAT   256
#define K_NB     8
#define G        16
#define NCELL    (G * G * G)      // 4096
#define PB_T     1024
#define PPT      (N_POINTS / PB_T) // 16 points per thread in block 0
#define CPT      (NCELL / PB_T)    // 4 cells per thread in the scan

__device__ __forceinline__ int clampi(int v, int lo, int hi) {
    return min(max(v, lo), hi);
}

// f32 -> bf16 round-to-nearest-even (inputs finite)
__device__ __forceinline__ unsigned short f32_to_bf16(float f) {
    const unsigned x = __float_as_uint(f);
    return (unsigned short)((x + 0x7FFFu + ((x >> 16) & 1u)) >> 16);
}
// bf16 -> f32 is a shift
__device__ __forceinline__ float bf16_to_f32(unsigned short h) {
    return __uint_as_float((unsigned)h << 16);
}

// ---------- prep_bin: block 0 = hist+scan+scatter (reg-resident);
// ----------           blocks 1..1024 = normalized bf16 feature copy ---------
__global__ __launch_bounds__(PB_T) void prep_bin_kernel(const float* __restrict__ coords,
                                                        const float* __restrict__ feat,
                                                        int* __restrict__ cell_start,
                                                        float4* __restrict__ sorted,
                                                        ushort4* __restrict__ feat16) {
    const int tid  = threadIdx.x;
    const int lane = tid & 63;
    const int wave = tid >> 6;

    if (blockIdx.x == 0) {
        __shared__ int h[NCELL];     // 16 KB
        __shared__ int cur[NCELL];   // 16 KB
        __shared__ int wt[16];

        for (int c = tid; c < NCELL; c += PB_T) h[c] = 0;

        // ---- burst-load all 16 points/thread into registers ----
        float px[PPT], py[PPT], pz[PPT];
        int   cc[PPT];
        #pragma unroll
        for (int t = 0; t < PPT; ++t) {
            const int i = tid + t * PB_T;
            px[t] = coords[3 * i];
            py[t] = coords[3 * i + 1];
            pz[t] = coords[3 * i + 2];
        }
        __syncthreads();             // h[] zeroed

        #pragma unroll
        for (int t = 0; t < PPT; ++t) {
            const int cx = clampi((int)(px[t] * (float)G), 0, G - 1);
            const int cy = clampi((int)(py[t] * (float)G), 0, G - 1);
            const int cz = clampi((int)(pz[t] * (float)G), 0, G - 1);
            cc[t] = (cz * G + cy) * G + cx;
            atomicAdd(&h[cc[t]], 1);
        }
        __syncthreads();

        // ---- exclusive scan: 4 cells per thread ----
        const int t4 = tid * CPT;
        int c[CPT];
        int tot = 0;
        #pragma unroll
        for (int k = 0; k < CPT; ++k) { c[k] = h[t4 + k]; tot += c[k]; }
        int v = tot;
        #pragma unroll
        for (int off = 1; off < 64; off <<= 1) {
            int o = __shfl_up(v, off, 64);
            if (lane >= off) v += o;
        }
        if (lane == 63) wt[wave] = v;
        __syncthreads();
        int woff = 0;
        #pragma unroll
        for (int w = 0; w < 16; ++w) woff += (w < wave) ? wt[w] : 0;
        int ex = woff + v - tot;
        #pragma unroll
        for (int k = 0; k < CPT; ++k) {
            cur[t4 + k] = ex;
            cell_start[t4 + k] = ex;
            ex += c[k];
        }
        if (tid == 0) cell_start[NCELL] = N_POINTS;
        __syncthreads();

        // ---- scatter straight from registers ----
        #pragma unroll
        for (int t = 0; t < PPT; ++t) {
            const int slot = atomicAdd(&cur[cc[t]], 1);
            sorted[slot] = make_float4(px[t], py[t], pz[t],
                                       __int_as_float(tid + t * PB_T));
        }
    } else {
        // ---- normalized bf16 copy: 16 rows per block, one row per wave ----
        const int row = (blockIdx.x - 1) * 16 + wave;
        const float4* f4 = reinterpret_cast<const float4*>(feat + (size_t)row * D_FEAT);
        float4 u = f4[lane];
        float s = u.x * u.x + u.y * u.y + u.z * u.z + u.w * u.w;
        #pragma unroll
        for (int off = 32; off > 0; off >>= 1) s += __shfl_xor(s, off, 64);
        const float rq = 1.0f / fmaxf(sqrtf(s), 1e-12f);   // all lanes
        ushort4 o;
        o.x = f32_to_bf16(u.x * rq);
        o.y = f32_to_bf16(u.y * rq);
        o.z = f32_to_bf16(u.z * rq);
        o.w = f32_to_bf16(u.w * rq);
        feat16[(size_t)row * 64 + lane] = o;               // 64 ushort4 per row
    }
}

// 32-bit key: truncated d2 bits (exp + 11 mantissa) << 14 | sorted index.
// d2 <= 0.047 in a 3x3x3 neighborhood of w=1/16, so (bits>>12)<<14 fits u32.
#define PROC32(p, idxv)                                                       \
    {                                                                         \
        const float _dx = (p).x - xi, _dy = (p).y - yi, _dz = (p).z - zi;     \
        const float _d2 = fmaf(_dx, _dx, fmaf(_dy, _dy, _dz * _dz));          \
        unsigned _key = ((__float_as_uint(_d2) >> 12) << 14) | (unsigned)(idxv); \
        _key = ((idxv) == q) ? 0xFFFFFFFFu : _key;                            \
        const unsigned _lo = min(_key, k0);                                   \
        const unsigned _hi = max(_key, k0);                                   \
        k0 = _lo;                                                             \
        k1 = min(_hi, k1);                                                    \
    }

// ---------- knn + cosine (bf16 unit rows): one wave per query ---------------
__global__ __launch_bounds__(256) void knn_cos_kernel(const float4* __restrict__ sorted,
                                                      const int* __restrict__ cell_start,
                                                      const ushort4* __restrict__ feat16,
                                                      float* __restrict__ partial) {
    const int tid  = threadIdx.x;
    const int lane = tid & 63;
    const int wave = tid >> 6;
    const int q    = blockIdx.x * 4 + wave;       // sorted position

    const float4 qp = sorted[q];
    const float xi = qp.x, yi = qp.y, zi = qp.z;
    const int qorig = __float_as_int(qp.w);
    const int cx = clampi((int)(xi * (float)G), 0, G - 1);
    const int cy = clampi((int)(yi * (float)G), 0, G - 1);
    const int cz = clampi((int)(zi * (float)G), 0, G - 1);
    const int x0 = max(cx - 1, 0), x1 = min(cx + 1, G - 1);

    // lanes 0..8 fetch the 9 segment bounds in parallel
    int sv = 0, ev = 0;
    {
        const int dz = lane / 3 - 1, dy = lane % 3 - 1;   // meaningful for lane<9
        const int z = cz + dz, y = cy + dy;
        const bool valid = (lane < 9) && z >= 0 && z < G && y >= 0 && y < G;
        if (valid) {
            const int rowb = (z * G + y) * G;
            sv = cell_start[rowb + x0];
            ev = cell_start[rowb + x1 + 1];
        }
    }

    int segS[9], segE[9];
    #pragma unroll
    for (int r = 0; r < 9; ++r) {
        segS[r] = __shfl(sv, r, 64);
        segE[r] = __shfl(ev, r, 64);
    }

    // ---- prefetch first 64 candidates of every segment (independent loads) --
    float4 pf[9];
    #pragma unroll
    for (int r = 0; r < 9; ++r) {
        const int idx = segS[r] + lane;
        pf[r] = sorted[min(idx, N_POINTS - 1)];   // clamped; masked in use
    }

    // ---- branchless per-lane top-2 over prefetched + tail candidates ----
    unsigned k0 = 0xFFFFFFFFu, k1 = 0xFFFFFFFFu;
    #pragma unroll
    for (int r = 0; r < 9; ++r) {
        const int idx = segS[r] + lane;
        if (idx < segE[r]) PROC32(pf[r], idx);
        // tail (segment longer than 64 points — very rare at G=16)
        for (int b = segS[r] + 64; b < segE[r]; b += 64) {
            const int idx2 = b + lane;
            if (idx2 < segE[r]) {
                const float4 p = sorted[idx2];
                PROC32(p, idx2);
            }
        }
    }

    // ---- merge: 8 rounds of 32-bit wave-min over per-lane heads ----
    int nb[8];
    #pragma unroll
    for (int r = 0; r < K_NB; ++r) {
        unsigned m = k0;
        #pragma unroll
        for (int off = 32; off > 0; off >>= 1)
            m = min(m, (unsigned)__shfl_xor((int)m, off, 64));
        const bool won = (k0 == m);
        k0 = won ? k1 : k0;
        k1 = won ? 0xFFFFFFFFu : k1;
        nb[r] = (int)(m & 0x3FFFu);               // sorted index of neighbor
    }

    // ---- gather neighbor orig ids (independent loads) ----
    int jj[8];
    #pragma unroll
    for (int r = 0; r < K_NB; ++r) jj[r] = __float_as_int(sorted[nb[r]].w);

    // ---- cosine: bf16 unit rows, single-value linear reduce ----
    const ushort4 a4 = feat16[(size_t)qorig * 64 + lane];
    const float ax = bf16_to_f32(a4.x), ay = bf16_to_f32(a4.y);
    const float az = bf16_to_f32(a4.z), aw = bf16_to_f32(a4.w);
    float racc = 0.0f;
    #pragma unroll
    for (int r = 0; r < K_NB; ++r) {
        const ushort4 b4 = feat16[(size_t)jj[r] * 64 + lane];
        racc = fmaf(ax, bf16_to_f32(b4.x),
               fmaf(ay, bf16_to_f32(b4.y),
               fmaf(az, bf16_to_f32(b4.z),
               fmaf(aw, bf16_to_f32(b4.w), racc))));
    }
    #pragma unroll
    for (int off = 32; off > 0; off >>= 1) racc += __shfl_xor(racc, off, 64);
    const float wval = (float)K_NB - racc;        // sum of (1 - cos)

    __shared__ float wacc[4];
    if (lane == 0) wacc[wave] = wval;
    __syncthreads();
    if (tid == 0)
        partial[blockIdx.x] = wacc[0] + wacc[1] + wacc[2] + wacc[3];
}

// ---------- final reduction (4096 partials, fixed order) --------------------
__global__ __launch_bounds__(256) void reduce_kernel(const float* __restrict__ partial,
                                                     float* __restrict__ out) {
    const int tid  = threadIdx.x;
    const int lane = tid & 63;
    const int wave = tid >> 6;
    float s = 0.0f;
    for (int j = tid; j < N_POINTS / 4; j += 256) s += partial[j];
    #pragma unroll
    for (int off = 32; off > 0; off >>= 1) s += __shfl_xor(s, off, 64);
    __shared__ float sm[4];
    if (lane == 0) sm[wave] = s;
    __syncthreads();
    if (tid == 0)
        out[0] = 0.02f * (sm[0] + sm[1] + sm[2] + sm[3]) / (float)(N_POINTS * K_NB);
}

// ---------- launch ----------------------------------------------------------
extern "C" void kernel_launch(void* const* d_in, const int* in_sizes, int n_in,
                              void* d_out, int out_size, void* d_ws, size_t ws_size,
                              hipStream_t stream) {
    const float* feat   = (const float*)d_in[0];   // (16384, 256) f32
    const float* coords = (const float*)d_in[1];   // (16384, 3)  f32
    float* out = (float*)d_out;

    char* ws = (char*)d_ws;
    float4*  sorted     = (float4*)ws;                           // 262144 B
    int*     cell_start = (int*)(ws + 262144);                   // 16388 B
    ushort4* feat16     = (ushort4*)(ws + 262144 + 16640);       // 8 MB (bf16 unit rows)
    float*   partial    = (float*)(ws + 262144 + 16640 + 8388608); // 16384 B

    prep_bin_kernel<<<1 + N_POINTS / 16, PB_T, 0, stream>>>(coords, feat,
                                                            cell_start, sorted, feat16);
    knn_cos_kernel<<<N_POINTS / 4, 256, 0, stream>>>(sorted, cell_start,
                                                     feat16, partial);
    reduce_kernel<<<1, 256, 0, stream>>>(partial, out);
}